// Round 1
// 644.844 us; speedup vs baseline: 1.1264x; 1.1264x over previous
//
#include <hip/hip_runtime.h>
#include <math.h>

#define TPB 256
#define F_IN 1433
#define KPAD 1440          // 45 * 32, zero-padded tail
#define NKT 45
#define ROWS 128

typedef __attribute__((ext_vector_type(8))) short bf16x8;
typedef __attribute__((ext_vector_type(4))) float f32x4;

static __device__ __forceinline__ short f2bf(float f) {
    unsigned u = __float_as_uint(f);
    unsigned r = (u + 0x7FFFu + ((u >> 16) & 1u)) >> 16;   // RNE
    return (short)r;
}

// Build W^T bf16 once: WT[col][k] with col 0..7 = w1[0][k][col], 8..15 = w1[1][k][col-8],
// 16..23 = root1[k][col-16], 24..31 = 0; k in [F_IN, KPAD) zero-padded.
__global__ __launch_bounds__(256) void prep_wt_kernel(
    const float* __restrict__ w1, const float* __restrict__ root1, short* __restrict__ WT)
{
    int i = blockIdx.x * 256 + threadIdx.x;
    if (i >= 32 * KPAD) return;
    int col = i / KPAD, k = i - col * KPAD;
    float v = 0.f;
    if (k < F_IN) {
        if (col < 8)       v = w1[(size_t)k * 8 + col];
        else if (col < 16) v = w1[(size_t)(F_IN + k) * 8 + (col - 8)];
        else if (col < 24) v = root1[(size_t)k * 8 + (col - 16)];
    }
    WT[i] = f2bf(v);
}

// ---------------- Fused: layer-1 GEMM (barrier-free, per-wave register pipeline)
// for blocks < NB1; dst-histogram for the rest
__global__ __launch_bounds__(256) void node1_hist_kernel(
    const float* __restrict__ x,      // [N][1433]
    const short* __restrict__ WT,     // [32][KPAD] bf16 (pre-transposed weights)
    const float* __restrict__ att1,   // [16]
    float* __restrict__ XW1,          // [N][16]
    float* __restrict__ H1,           // [N][8]
    float2* __restrict__ SC1,
    float* __restrict__ HA1,
    const int* __restrict__ ei,       // [2][E]
    int* __restrict__ cnt,            // [N]
    int N, int E, int NB1)
{
    __shared__ float dump[ROWS * 25];   // 12.8 KB, epilogue only

    const int tid = threadIdx.x;
    const int bid = blockIdx.x;

    if (bid >= NB1) {   // -------- histogram path
        int e = (bid - NB1) * TPB + tid;
        if (e < E) atomicAdd(&cnt[ei[(size_t)E + e]], 1);
        return;
    }

    const int wv   = tid >> 6;
    const int lane = tid & 63;
    const int rowbase = bid * ROWS;

    // A-fragment mapping (verified): row = lane&15 (+16 for second tile), k = (lane>>4)*8 .. +7
    int r0 = rowbase + wv * 32 + (lane & 15);
    int r1 = r0 + 16;
    if (r0 >= N) r0 = N - 1;
    if (r1 >= N) r1 = N - 1;
    const float* xr0 = x + (size_t)r0 * F_IN;
    const float* xr1 = x + (size_t)r1 * F_IN;
    const int klane = (lane >> 4) << 3;
    // B-fragment mapping: col = lane&15 (+16), k = (lane>>4)*8 .. +7
    const short* wt0 = WT + (size_t)(lane & 15) * KPAD;
    const short* wt1 = wt0 + 16 * KPAD;

    f32x4 acc[2][2];
#pragma unroll
    for (int i = 0; i < 2; ++i)
#pragma unroll
        for (int j = 0; j < 2; ++j)
#pragma unroll
            for (int r = 0; r < 4; ++r) acc[i][j][r] = 0.f;

#define LOADA(c, A0, A1) do {                                                  \
        int kf = (c) * 32 + klane;                                             \
        if (kf + 8 <= F_IN) {                                                  \
            float4 u0 = *reinterpret_cast<const float4*>(xr0 + kf);            \
            float4 u1 = *reinterpret_cast<const float4*>(xr0 + kf + 4);        \
            float4 v0 = *reinterpret_cast<const float4*>(xr1 + kf);            \
            float4 v1 = *reinterpret_cast<const float4*>(xr1 + kf + 4);        \
            A0[0] = u0.x; A0[1] = u0.y; A0[2] = u0.z; A0[3] = u0.w;            \
            A0[4] = u1.x; A0[5] = u1.y; A0[6] = u1.z; A0[7] = u1.w;            \
            A1[0] = v0.x; A1[1] = v0.y; A1[2] = v0.z; A1[3] = v0.w;            \
            A1[4] = v1.x; A1[5] = v1.y; A1[6] = v1.z; A1[7] = v1.w;            \
        } else {                                                               \
            _Pragma("unroll")                                                  \
            for (int q = 0; q < 8; ++q) {                                      \
                A0[q] = (kf + q < F_IN) ? xr0[kf + q] : 0.f;                   \
                A1[q] = (kf + q < F_IN) ? xr1[kf + q] : 0.f;                   \
            }                                                                  \
        }                                                                      \
    } while (0)

#define LOADB(c, B0, B1) do {                                                  \
        int kf = (c) * 32 + klane;                                             \
        B0 = *reinterpret_cast<const bf16x8*>(wt0 + kf);                       \
        B1 = *reinterpret_cast<const bf16x8*>(wt1 + kf);                       \
    } while (0)

#define COMPUTE(A0, A1, B0, B1) do {                                           \
        bf16x8 pa0, pa1;                                                       \
        _Pragma("unroll")                                                      \
        for (int q = 0; q < 8; ++q) { pa0[q] = f2bf(A0[q]); pa1[q] = f2bf(A1[q]); } \
        acc[0][0] = __builtin_amdgcn_mfma_f32_16x16x32_bf16(pa0, B0, acc[0][0], 0, 0, 0); \
        acc[0][1] = __builtin_amdgcn_mfma_f32_16x16x32_bf16(pa0, B1, acc[0][1], 0, 0, 0); \
        acc[1][0] = __builtin_amdgcn_mfma_f32_16x16x32_bf16(pa1, B0, acc[1][0], 0, 0, 0); \
        acc[1][1] = __builtin_amdgcn_mfma_f32_16x16x32_bf16(pa1, B1, acc[1][1], 0, 0, 0); \
    } while (0)

    // Two static register sets (no runtime indexing -> no scratch), 1-tile-ahead pipeline.
    float a0A[8], a1A[8], a0B[8], a1B[8];
    bf16x8 b0A, b1A, b0B, b1B;

    LOADA(0, a0A, a1A);
    LOADB(0, b0A, b1A);
    for (int c = 0; c < NKT; c += 2) {
        if (c + 1 < NKT) { LOADA(c + 1, a0B, a1B); LOADB(c + 1, b0B, b1B); }
        COMPUTE(a0A, a1A, b0A, b1A);
        if (c + 1 < NKT) {
            if (c + 2 < NKT) { LOADA(c + 2, a0A, a1A); LOADB(c + 2, b0A, b1A); }
            COMPUTE(a0B, a1B, b0B, b1B);
        }
    }
#undef LOADA
#undef LOADB
#undef COMPUTE

    // dump accs: C/D layout col=lane&15, row=(lane>>4)*4+reg  [m89-verified]
#pragma unroll
    for (int rt = 0; rt < 2; ++rt)
#pragma unroll
        for (int ot = 0; ot < 2; ++ot) {
            int col = ot * 16 + (lane & 15);
            if (col < 24) {
#pragma unroll
                for (int r = 0; r < 4; ++r) {
                    int row = wv * 32 + rt * 16 + (lane >> 4) * 4 + r;
                    dump[row * 25 + col] = acc[rt][ot][r];
                }
            }
        }
    __syncthreads();

    if (tid < ROWS) {
        int n = rowbase + tid;
        if (n < N) {
            float sum[24];
#pragma unroll
            for (int j = 0; j < 24; ++j) sum[j] = dump[tid * 25 + j];
            float s0 = 0.f, s1 = 0.f, ha = 0.f;
#pragma unroll
            for (int j = 0; j < 8; ++j) {
                s0 += sum[j] * att1[j];
                s1 += sum[8 + j] * att1[j];
                ha += sum[16 + j] * att1[8 + j];
            }
            float4* xwout = reinterpret_cast<float4*>(XW1 + (size_t)n * 16);
            xwout[0] = make_float4(sum[0], sum[1], sum[2], sum[3]);
            xwout[1] = make_float4(sum[4], sum[5], sum[6], sum[7]);
            xwout[2] = make_float4(sum[8], sum[9], sum[10], sum[11]);
            xwout[3] = make_float4(sum[12], sum[13], sum[14], sum[15]);
            float4* hout = reinterpret_cast<float4*>(H1 + (size_t)n * 8);
            hout[0] = make_float4(sum[16], sum[17], sum[18], sum[19]);
            hout[1] = make_float4(sum[20], sum[21], sum[22], sum[23]);
            SC1[n] = make_float2(s0, s1);
            HA1[n] = ha;
        }
    }
}

__global__ __launch_bounds__(256) void scanA_kernel(
    const int* __restrict__ cnt, int* __restrict__ rowptr, int* __restrict__ bsums, int N)
{
    __shared__ int lds[256];
    int t = threadIdx.x;
    int base = blockIdx.x * 1024 + t * 4;
    int c[4];
#pragma unroll
    for (int j = 0; j < 4; ++j) c[j] = (base + j < N) ? cnt[base + j] : 0;
    int tsum = c[0] + c[1] + c[2] + c[3];
    lds[t] = tsum;
    __syncthreads();
    for (int off = 1; off < 256; off <<= 1) {
        int v = (t >= off) ? lds[t - off] : 0;
        __syncthreads();
        lds[t] += v;
        __syncthreads();
    }
    int run = lds[t] - tsum;
#pragma unroll
    for (int j = 0; j < 4; ++j) {
        if (base + j < N) rowptr[base + j] = run;
        run += c[j];
    }
    if (t == 255) bsums[blockIdx.x] = lds[255];
}

__global__ __launch_bounds__(128) void scanB_kernel(int* __restrict__ bsums, int nb)
{
    __shared__ int lds[128];
    int t = threadIdx.x;
    int v = (t < nb) ? bsums[t] : 0;
    lds[t] = v;
    __syncthreads();
    for (int off = 1; off < 128; off <<= 1) {
        int w = (t >= off) ? lds[t - off] : 0;
        __syncthreads();
        lds[t] += w;
        __syncthreads();
    }
    if (t < nb) bsums[t] = lds[t] - v;
}

__global__ __launch_bounds__(256) void scanC_kernel(
    int* __restrict__ rowptr, int* __restrict__ cnt, const int* __restrict__ bsums, int N, int E)
{
    int i = blockIdx.x * TPB + threadIdx.x;
    if (i < N) {
        int v = rowptr[i] + bsums[i >> 10];
        rowptr[i] = v;
        cnt[i] = v;
    }
    if (i == 0) rowptr[N] = E;
}

__global__ __launch_bounds__(256) void scatter_kernel(
    const int* __restrict__ ei, const float* __restrict__ pseudo,
    int* __restrict__ cursor, int2* __restrict__ recs, int E)
{
    int e = blockIdx.x * TPB + threadIdx.x;
    if (e >= E) return;
    int s = ei[e];
    int d = ei[(size_t)E + e];
    float u = pseudo[e];
    int pos = atomicAdd(&cursor[d], 1);
    recs[pos] = make_int2(s, __float_as_int(u));
}

// ---------------- Gather layer-1 (16 lanes per node) + fused node2 epilogue
__global__ __launch_bounds__(256) void gather1_kernel(
    const int* __restrict__ rowptr, const int2* __restrict__ recs,
    const float4* __restrict__ XW1v,
    const float2* __restrict__ SC1, const float* __restrict__ HA1,
    const float* __restrict__ H1, const float* __restrict__ bias1,
    const float* __restrict__ w2, const float* __restrict__ root2, const float* __restrict__ att2,
    float* __restrict__ XW2, float* __restrict__ H2, float2* __restrict__ SC2, float* __restrict__ HA2,
    int N)
{
    int tid = blockIdx.x * TPB + threadIdx.x;
    int n = tid >> 4;
    int lane = tid & 15;
    if (n >= N) return;
    int start = rowptr[n], end = rowptr[n + 1];
    float ha = HA1[n];
    float den = 0.f;
    float num[8];
#pragma unroll
    for (int j = 0; j < 8; ++j) num[j] = 0.f;

    for (int i = start + lane; i < end; i += 16) {
        int2 r = recs[i];
        int s = r.x;
        float u = __int_as_float(r.y);
        float um = 1.f - u;
        float2 sc = SC1[s];
        float raw = um * sc.x + u * sc.y + ha;
        float score = (raw > 0.f) ? raw : 0.2f * raw;
        float w = expf(score);
        const float4* xw = XW1v + (size_t)s * 4;
        float4 p0 = xw[0], p1 = xw[1], q0 = xw[2], q1 = xw[3];
        num[0] = fmaf(w, um * p0.x + u * q0.x, num[0]);
        num[1] = fmaf(w, um * p0.y + u * q0.y, num[1]);
        num[2] = fmaf(w, um * p0.z + u * q0.z, num[2]);
        num[3] = fmaf(w, um * p0.w + u * q0.w, num[3]);
        num[4] = fmaf(w, um * p1.x + u * q1.x, num[4]);
        num[5] = fmaf(w, um * p1.y + u * q1.y, num[5]);
        num[6] = fmaf(w, um * p1.z + u * q1.z, num[6]);
        num[7] = fmaf(w, um * p1.w + u * q1.w, num[7]);
        den += w;
    }
#pragma unroll
    for (int off = 1; off < 16; off <<= 1) {
#pragma unroll
        for (int j = 0; j < 8; ++j) num[j] += __shfl_xor(num[j], off);
        den += __shfl_xor(den, off);
    }
    if (lane != 0) return;

    float inv = 1.f / (den + 1e-16f);
    float hp[8];
#pragma unroll
    for (int j = 0; j < 8; ++j) {
        float o = num[j] * inv + H1[(size_t)n * 8 + j] + bias1[j];
        hp[j] = (o > 0.f) ? o : expm1f(o);
    }
    float a[7], b[7], h[7];
#pragma unroll
    for (int j2 = 0; j2 < 7; ++j2) { a[j2] = 0.f; b[j2] = 0.f; h[j2] = 0.f; }
#pragma unroll
    for (int j = 0; j < 8; ++j) {
#pragma unroll
        for (int j2 = 0; j2 < 7; ++j2) {
            a[j2] = fmaf(hp[j], w2[j * 7 + j2], a[j2]);
            b[j2] = fmaf(hp[j], w2[56 + j * 7 + j2], b[j2]);
            h[j2] = fmaf(hp[j], root2[j * 7 + j2], h[j2]);
        }
    }
    float s0 = 0.f, s1 = 0.f, hA = 0.f;
#pragma unroll
    for (int j2 = 0; j2 < 7; ++j2) {
        s0 += a[j2] * att2[j2];
        s1 += b[j2] * att2[j2];
        hA += h[j2] * att2[7 + j2];
    }
    float4* xwout = reinterpret_cast<float4*>(XW2 + (size_t)n * 16);
    xwout[0] = make_float4(a[0], a[1], a[2], a[3]);
    xwout[1] = make_float4(a[4], a[5], a[6], 0.f);
    xwout[2] = make_float4(b[0], b[1], b[2], b[3]);
    xwout[3] = make_float4(b[4], b[5], b[6], 0.f);
    float4* hout = reinterpret_cast<float4*>(H2 + (size_t)n * 8);
    hout[0] = make_float4(h[0], h[1], h[2], h[3]);
    hout[1] = make_float4(h[4], h[5], h[6], 0.f);
    SC2[n] = make_float2(s0, s1);
    HA2[n] = hA;
}

// ---------------- Gather layer-2 (16 lanes per node) + fused log_softmax
__global__ __launch_bounds__(256) void gather2_kernel(
    const int* __restrict__ rowptr, const int2* __restrict__ recs,
    const float4* __restrict__ XW2v,
    const float2* __restrict__ SC2, const float* __restrict__ HA2,
    const float* __restrict__ H2, const float* __restrict__ bias2,
    float* __restrict__ out, int N)
{
    int tid = blockIdx.x * TPB + threadIdx.x;
    int n = tid >> 4;
    int lane = tid & 15;
    if (n >= N) return;
    int start = rowptr[n], end = rowptr[n + 1];
    float ha = HA2[n];
    float den = 0.f;
    float num[7];
#pragma unroll
    for (int j = 0; j < 7; ++j) num[j] = 0.f;

    for (int i = start + lane; i < end; i += 16) {
        int2 r = recs[i];
        int s = r.x;
        float u = __int_as_float(r.y);
        float um = 1.f - u;
        float2 sc = SC2[s];
        float raw = um * sc.x + u * sc.y + ha;
        float score = (raw > 0.f) ? raw : 0.2f * raw;
        float w = expf(score);
        const float4* xw = XW2v + (size_t)s * 4;
        float4 p0 = xw[0], p1 = xw[1], q0 = xw[2], q1 = xw[3];
        num[0] = fmaf(w, um * p0.x + u * q0.x, num[0]);
        num[1] = fmaf(w, um * p0.y + u * q0.y, num[1]);
        num[2] = fmaf(w, um * p0.z + u * q0.z, num[2]);
        num[3] = fmaf(w, um * p0.w + u * q0.w, num[3]);
        num[4] = fmaf(w, um * p1.x + u * q1.x, num[4]);
        num[5] = fmaf(w, um * p1.y + u * q1.y, num[5]);
        num[6] = fmaf(w, um * p1.z + u * q1.z, num[6]);
        den += w;
    }
#pragma unroll
    for (int off = 1; off < 16; off <<= 1) {
#pragma unroll
        for (int j = 0; j < 7; ++j) num[j] += __shfl_xor(num[j], off);
        den += __shfl_xor(den, off);
    }
    if (lane != 0) return;

    float inv = 1.f / (den + 1e-16f);
    float o[7];
    float mx = -1e30f;
#pragma unroll
    for (int j = 0; j < 7; ++j) {
        o[j] = fmaf(num[j], inv, H2[(size_t)n * 8 + j] + bias2[j]);
        mx = fmaxf(mx, o[j]);
    }
    float sum = 0.f;
#pragma unroll
    for (int j = 0; j < 7; ++j) sum += expf(o[j] - mx);
    float lse = mx + logf(sum);
#pragma unroll
    for (int j = 0; j < 7; ++j) out[(size_t)n * 7 + j] = o[j] - lse;
}

extern "C" void kernel_launch(void* const* d_in, const int* in_sizes, int n_in,
                              void* d_out, int out_size, void* d_ws, size_t ws_size,
                              hipStream_t stream) {
    const float* x      = (const float*)d_in[0];
    const int*   ei     = (const int*)d_in[1];
    const float* pseudo = (const float*)d_in[2];
    const float* w1     = (const float*)d_in[3];
    const float* root1  = (const float*)d_in[4];
    const float* att1   = (const float*)d_in[5];
    const float* bias1  = (const float*)d_in[6];
    const float* w2     = (const float*)d_in[7];
    const float* root2  = (const float*)d_in[8];
    const float* att2   = (const float*)d_in[9];
    const float* bias2  = (const float*)d_in[10];

    const int N = in_sizes[0] / F_IN;
    const int E = in_sizes[2];
    const size_t Ns = (size_t)N;

    float* ws   = (float*)d_ws;
    float* XW1  = ws;                       // 16N
    float* H1   = XW1 + 16 * Ns;            // 8N
    float2* SC1 = (float2*)(H1 + 8 * Ns);   // 2N floats
    float* HA1  = (float*)SC1 + 2 * Ns;     // N
    float* XW2  = HA1 + Ns;                 // 16N
    float* H2   = XW2 + 16 * Ns;            // 8N
    float2* SC2 = (float2*)(H2 + 8 * Ns);   // 2N
    float* HA2  = (float*)SC2 + 2 * Ns;     // N
    int*   cnt    = (int*)(HA2 + Ns);       // N
    int*   rowptr = cnt + Ns;               // N+1
    int*   bsums  = rowptr + Ns + 1;        // 128
    size_t off = (size_t)(bsums + 128) - (size_t)d_ws;
    off = (off + 7) & ~(size_t)7;
    int2*  recs = (int2*)((char*)d_ws + off);  // E records
    size_t woff = off + (size_t)E * sizeof(int2);
    woff = (woff + 15) & ~(size_t)15;
    short* WT = (short*)((char*)d_ws + woff);  // 32*KPAD bf16 (92 KB)

    int nblk  = (N + TPB - 1) / TPB;
    int eblk  = (E + TPB - 1) / TPB;
    int sblkA = (N + 1023) / 1024;
    int nb1   = (N + ROWS - 1) / ROWS;
    int gblk  = ((N * 16) + TPB - 1) / TPB;
    int wblk  = (32 * KPAD + TPB - 1) / TPB;

    hipMemsetAsync(cnt, 0, Ns * sizeof(int), stream);

    prep_wt_kernel<<<wblk, TPB, 0, stream>>>(w1, root1, WT);
    node1_hist_kernel<<<nb1 + eblk, TPB, 0, stream>>>(
        x, WT, att1, XW1, H1, SC1, HA1, ei, cnt, N, E, nb1);
    scanA_kernel<<<sblkA, TPB, 0, stream>>>(cnt, rowptr, bsums, N);
    scanB_kernel<<<1, 128, 0, stream>>>(bsums, sblkA);
    scanC_kernel<<<nblk, TPB, 0, stream>>>(rowptr, cnt, bsums, N, E);
    scatter_kernel<<<eblk, TPB, 0, stream>>>(ei, pseudo, cnt, recs, E);
    gather1_kernel<<<gblk, TPB, 0, stream>>>(rowptr, recs, (const float4*)XW1, SC1, HA1,
                                             H1, bias1, w2, root2, att2,
                                             XW2, H2, SC2, HA2, N);
    gather2_kernel<<<gblk, TPB, 0, stream>>>(rowptr, recs, (const float4*)XW2, SC2, HA2,
                                             H2, bias2, (float*)d_out, N);
}

// Round 2
// 611.143 us; speedup vs baseline: 1.1885x; 1.0551x over previous
//
#include <hip/hip_runtime.h>
#include <math.h>

#define TPB 256
#define F_IN 1433
#define KPAD 1440          // 45 * 32, zero-padded tail
#define NT 45              // total k-tiles of 32 floats
#define NFULL 44           // tiles staged via LDS (k 0..1407); tail tile masked in regs
#define ROWS 128

typedef __attribute__((ext_vector_type(8))) short bf16x8;
typedef __attribute__((ext_vector_type(4))) float f32x4;

static __device__ __forceinline__ short f2bf(float f) {
    unsigned u = __float_as_uint(f);
    unsigned r = (u + 0x7FFFu + ((u >> 16) & 1u)) >> 16;   // RNE
    return (short)r;
}

// Build W^T bf16 once + zero the degree counters (replaces hipMemsetAsync).
// WT[col][k]: col 0..7 = w1[0][k][col], 8..15 = w1[1][k][col-8], 16..23 = root1[k][col-16],
// 24..31 = 0; k in [F_IN, KPAD) zero-padded.
__global__ __launch_bounds__(256) void prep_kernel(
    const float* __restrict__ w1, const float* __restrict__ root1,
    short* __restrict__ WT, int* __restrict__ cnt, int N)
{
    int i = blockIdx.x * 256 + threadIdx.x;
    if (i < N) cnt[i] = 0;
    if (i < 32 * KPAD) {
        int col = i / KPAD, k = i - col * KPAD;
        float v = 0.f;
        if (k < F_IN) {
            if (col < 8)       v = w1[(size_t)k * 8 + col];
            else if (col < 16) v = w1[(size_t)(F_IN + k) * 8 + (col - 8)];
            else if (col < 24) v = root1[(size_t)k * 8 + (col - 16)];
        }
        WT[i] = f2bf(v);
    }
}

// ---------------- Fused: layer-1 GEMM for blocks < NB1; dst-histogram for the rest.
// GEMM path: barrier-free per-wave LDS staging (T14 issue-early/write-late), XOR-swizzled.
__global__ __launch_bounds__(256) void node1_hist_kernel(
    const float* __restrict__ x,      // [N][1433]
    const short* __restrict__ WT,     // [32][KPAD] bf16 (pre-transposed weights)
    const float* __restrict__ att1,   // [16]
    float* __restrict__ XW1,          // [N][16]
    float* __restrict__ H1,           // [N][8]
    float2* __restrict__ SC1,
    float* __restrict__ HA1,
    const int* __restrict__ ei,       // [2][E]
    int* __restrict__ cnt,            // [N]
    int N, int E, int NB1)
{
    // Wave-private staging: xb[wv] = 32 rows x 32 k f32, chunk-XOR-swizzled.
    // Reused as the epilogue dump buffer (needs 3200 f32 <= 4096).
    __shared__ float xb[4][32][32];   // 16 KB

    const int tid = threadIdx.x;
    const int bid = blockIdx.x;

    if (bid >= NB1) {   // -------- histogram path
        int e = (bid - NB1) * TPB + tid;
        if (e < E) atomicAdd(&cnt[ei[(size_t)E + e]], 1);
        return;
    }

    const int wv   = tid >> 6;
    const int lane = tid & 63;
    const int rowbase = bid * ROWS;

    // ---- staging lane map: lane covers (row8 = lane&7, logical chunk = lane>>3);
    //      4 groups g cover rows g*8+row8. Write to physical chunk = c ^ row8.
    const int srow   = lane & 7;
    const int schunk = lane >> 3;
    const int pchunk = schunk ^ srow;
    const float* gsrc[4];
#pragma unroll
    for (int g = 0; g < 4; ++g) {
        int r = rowbase + wv * 32 + g * 8 + srow;
        if (r >= N) r = N - 1;
        gsrc[g] = x + (size_t)r * F_IN + schunk * 4;
    }

    // ---- compute-side fragment map (16x16x32 bf16, m89-verified):
    //      A rows r0=lane&15 (tile0) / r0+16 (tile1), k = (lane>>4)*8 .. +7
    const int r0 = lane & 15, r1 = r0 + 16;
    const int klane = (lane >> 4) * 8;
    const int c0 = klane >> 2;               // even logical chunk
    const int p0 = c0 ^ (r0 & 7);            // r1&7 == r0&7
    const int p1 = (c0 + 1) ^ (r0 & 7);
    const short* wt0 = WT + (size_t)(lane & 15) * KPAD + klane;
    const short* wt1 = wt0 + 16 * KPAD;

    f32x4 acc[2][2];
#pragma unroll
    for (int i = 0; i < 2; ++i)
#pragma unroll
        for (int j = 0; j < 2; ++j)
#pragma unroll
            for (int r = 0; r < 4; ++r) acc[i][j][r] = 0.f;

    // prologue: stage tile 0
    {
        float4 V[4];
#pragma unroll
        for (int g = 0; g < 4; ++g) V[g] = *reinterpret_cast<const float4*>(gsrc[g]);
#pragma unroll
        for (int g = 0; g < 4; ++g)
            *reinterpret_cast<float4*>(&xb[wv][g * 8 + srow][pchunk * 4]) = V[g];
    }

    for (int t = 0; t < NFULL; ++t) {
        // issue next tile's global loads early (in flight during compute)
        float4 Vn[4];
        const bool more = (t + 1 < NFULL);
        if (more) {
#pragma unroll
            for (int g = 0; g < 4; ++g)
                Vn[g] = *reinterpret_cast<const float4*>(gsrc[g] + (t + 1) * 32);
        }
        // B fragments for tile t (L2-hot WT)
        bf16x8 b0 = *reinterpret_cast<const bf16x8*>(wt0 + t * 32);
        bf16x8 b1 = *reinterpret_cast<const bf16x8*>(wt1 + t * 32);
        // LDS -> A fragments (swizzled 16B reads, <=2-way conflicts)
        float4 fa0 = *reinterpret_cast<const float4*>(&xb[wv][r0][p0 * 4]);
        float4 fb0 = *reinterpret_cast<const float4*>(&xb[wv][r0][p1 * 4]);
        float4 fa1 = *reinterpret_cast<const float4*>(&xb[wv][r1][p0 * 4]);
        float4 fb1 = *reinterpret_cast<const float4*>(&xb[wv][r1][p1 * 4]);
        bf16x8 pa0, pa1;
        pa0[0] = f2bf(fa0.x); pa0[1] = f2bf(fa0.y); pa0[2] = f2bf(fa0.z); pa0[3] = f2bf(fa0.w);
        pa0[4] = f2bf(fb0.x); pa0[5] = f2bf(fb0.y); pa0[6] = f2bf(fb0.z); pa0[7] = f2bf(fb0.w);
        pa1[0] = f2bf(fa1.x); pa1[1] = f2bf(fa1.y); pa1[2] = f2bf(fa1.z); pa1[3] = f2bf(fa1.w);
        pa1[4] = f2bf(fb1.x); pa1[5] = f2bf(fb1.y); pa1[6] = f2bf(fb1.z); pa1[7] = f2bf(fb1.w);
        acc[0][0] = __builtin_amdgcn_mfma_f32_16x16x32_bf16(pa0, b0, acc[0][0], 0, 0, 0);
        acc[0][1] = __builtin_amdgcn_mfma_f32_16x16x32_bf16(pa0, b1, acc[0][1], 0, 0, 0);
        acc[1][0] = __builtin_amdgcn_mfma_f32_16x16x32_bf16(pa1, b0, acc[1][0], 0, 0, 0);
        acc[1][1] = __builtin_amdgcn_mfma_f32_16x16x32_bf16(pa1, b1, acc[1][1], 0, 0, 0);
        // write next tile into the (wave-private) buffer after this tile's reads
        if (more) {
#pragma unroll
            for (int g = 0; g < 4; ++g)
                *reinterpret_cast<float4*>(&xb[wv][g * 8 + srow][pchunk * 4]) = Vn[g];
        }
    }

    // ---- tail tile (k 1408..1432): masked per-lane register loads (keeps zero-padded
    //      WT away from potentially-poisoned out-of-bounds A bytes)
    {
        int rr0 = rowbase + wv * 32 + r0; if (rr0 >= N) rr0 = N - 1;
        int rr1 = rowbase + wv * 32 + r1; if (rr1 >= N) rr1 = N - 1;
        const float* xr0 = x + (size_t)rr0 * F_IN;
        const float* xr1 = x + (size_t)rr1 * F_IN;
        const int kf = NFULL * 32 + klane;
        bf16x8 pa0, pa1;
#pragma unroll
        for (int q = 0; q < 8; ++q) {
            float v0 = (kf + q < F_IN) ? xr0[kf + q] : 0.f;
            float v1 = (kf + q < F_IN) ? xr1[kf + q] : 0.f;
            pa0[q] = f2bf(v0);
            pa1[q] = f2bf(v1);
        }
        bf16x8 b0 = *reinterpret_cast<const bf16x8*>(wt0 + NFULL * 32);
        bf16x8 b1 = *reinterpret_cast<const bf16x8*>(wt1 + NFULL * 32);
        acc[0][0] = __builtin_amdgcn_mfma_f32_16x16x32_bf16(pa0, b0, acc[0][0], 0, 0, 0);
        acc[0][1] = __builtin_amdgcn_mfma_f32_16x16x32_bf16(pa0, b1, acc[0][1], 0, 0, 0);
        acc[1][0] = __builtin_amdgcn_mfma_f32_16x16x32_bf16(pa1, b0, acc[1][0], 0, 0, 0);
        acc[1][1] = __builtin_amdgcn_mfma_f32_16x16x32_bf16(pa1, b1, acc[1][1], 0, 0, 0);
    }

    __syncthreads();   // xb reused cross-wave as dump buffer below

    // dump accs: C/D layout col=lane&15, row=(lane>>4)*4+reg  [m89-verified]
    float* dump = reinterpret_cast<float*>(xb);   // 128 x 25 f32 = 12.8 KB
#pragma unroll
    for (int rt = 0; rt < 2; ++rt)
#pragma unroll
        for (int ot = 0; ot < 2; ++ot) {
            int col = ot * 16 + (lane & 15);
            if (col < 24) {
#pragma unroll
                for (int r = 0; r < 4; ++r) {
                    int row = wv * 32 + rt * 16 + (lane >> 4) * 4 + r;
                    dump[row * 25 + col] = acc[rt][ot][r];
                }
            }
        }
    __syncthreads();

    if (tid < ROWS) {
        int n = rowbase + tid;
        if (n < N) {
            float sum[24];
#pragma unroll
            for (int j = 0; j < 24; ++j) sum[j] = dump[tid * 25 + j];
            float s0 = 0.f, s1 = 0.f, ha = 0.f;
#pragma unroll
            for (int j = 0; j < 8; ++j) {
                s0 += sum[j] * att1[j];
                s1 += sum[8 + j] * att1[j];
                ha += sum[16 + j] * att1[8 + j];
            }
            float4* xwout = reinterpret_cast<float4*>(XW1 + (size_t)n * 16);
            xwout[0] = make_float4(sum[0], sum[1], sum[2], sum[3]);
            xwout[1] = make_float4(sum[4], sum[5], sum[6], sum[7]);
            xwout[2] = make_float4(sum[8], sum[9], sum[10], sum[11]);
            xwout[3] = make_float4(sum[12], sum[13], sum[14], sum[15]);
            float4* hout = reinterpret_cast<float4*>(H1 + (size_t)n * 8);
            hout[0] = make_float4(sum[16], sum[17], sum[18], sum[19]);
            hout[1] = make_float4(sum[20], sum[21], sum[22], sum[23]);
            SC1[n] = make_float2(s0, s1);
            HA1[n] = ha;
        }
    }
}

__global__ __launch_bounds__(256) void scanA_kernel(
    const int* __restrict__ cnt, int* __restrict__ rowptr, int* __restrict__ bsums, int N)
{
    __shared__ int lds[256];
    int t = threadIdx.x;
    int base = blockIdx.x * 1024 + t * 4;
    int c[4];
#pragma unroll
    for (int j = 0; j < 4; ++j) c[j] = (base + j < N) ? cnt[base + j] : 0;
    int tsum = c[0] + c[1] + c[2] + c[3];
    lds[t] = tsum;
    __syncthreads();
    for (int off = 1; off < 256; off <<= 1) {
        int v = (t >= off) ? lds[t - off] : 0;
        __syncthreads();
        lds[t] += v;
        __syncthreads();
    }
    int run = lds[t] - tsum;
#pragma unroll
    for (int j = 0; j < 4; ++j) {
        if (base + j < N) rowptr[base + j] = run;
        run += c[j];
    }
    if (t == 255) bsums[blockIdx.x] = lds[255];
}

__global__ __launch_bounds__(128) void scanB_kernel(int* __restrict__ bsums, int nb)
{
    __shared__ int lds[128];
    int t = threadIdx.x;
    int v = (t < nb) ? bsums[t] : 0;
    lds[t] = v;
    __syncthreads();
    for (int off = 1; off < 128; off <<= 1) {
        int w = (t >= off) ? lds[t - off] : 0;
        __syncthreads();
        lds[t] += w;
        __syncthreads();
    }
    if (t < nb) bsums[t] = lds[t] - v;
}

__global__ __launch_bounds__(256) void scanC_kernel(
    int* __restrict__ rowptr, int* __restrict__ cnt, const int* __restrict__ bsums, int N, int E)
{
    int i = blockIdx.x * TPB + threadIdx.x;
    if (i < N) {
        int v = rowptr[i] + bsums[i >> 10];
        rowptr[i] = v;
        cnt[i] = v;
    }
    if (i == 0) rowptr[N] = E;
}

__global__ __launch_bounds__(256) void scatter_kernel(
    const int* __restrict__ ei, const float* __restrict__ pseudo,
    int* __restrict__ cursor, int2* __restrict__ recs, int E)
{
    int e = blockIdx.x * TPB + threadIdx.x;
    if (e >= E) return;
    int s = ei[e];
    int d = ei[(size_t)E + e];
    float u = pseudo[e];
    int pos = atomicAdd(&cursor[d], 1);
    recs[pos] = make_int2(s, __float_as_int(u));
}

// ---------------- Gather layer-1 (16 lanes per node) + fused node2 epilogue
__global__ __launch_bounds__(256) void gather1_kernel(
    const int* __restrict__ rowptr, const int2* __restrict__ recs,
    const float4* __restrict__ XW1v,
    const float2* __restrict__ SC1, const float* __restrict__ HA1,
    const float* __restrict__ H1, const float* __restrict__ bias1,
    const float* __restrict__ w2, const float* __restrict__ root2, const float* __restrict__ att2,
    float* __restrict__ XW2, float* __restrict__ H2, float2* __restrict__ SC2, float* __restrict__ HA2,
    int N)
{
    int tid = blockIdx.x * TPB + threadIdx.x;
    int n = tid >> 4;
    int lane = tid & 15;
    if (n >= N) return;
    int start = rowptr[n], end = rowptr[n + 1];
    float ha = HA1[n];
    float den = 0.f;
    float num[8];
#pragma unroll
    for (int j = 0; j < 8; ++j) num[j] = 0.f;

    for (int i = start + lane; i < end; i += 16) {
        int2 r = recs[i];
        int s = r.x;
        float u = __int_as_float(r.y);
        float um = 1.f - u;
        float2 sc = SC1[s];
        float raw = um * sc.x + u * sc.y + ha;
        float score = (raw > 0.f) ? raw : 0.2f * raw;
        float w = expf(score);
        const float4* xw = XW1v + (size_t)s * 4;
        float4 p0 = xw[0], p1 = xw[1], q0 = xw[2], q1 = xw[3];
        num[0] = fmaf(w, um * p0.x + u * q0.x, num[0]);
        num[1] = fmaf(w, um * p0.y + u * q0.y, num[1]);
        num[2] = fmaf(w, um * p0.z + u * q0.z, num[2]);
        num[3] = fmaf(w, um * p0.w + u * q0.w, num[3]);
        num[4] = fmaf(w, um * p1.x + u * q1.x, num[4]);
        num[5] = fmaf(w, um * p1.y + u * q1.y, num[5]);
        num[6] = fmaf(w, um * p1.z + u * q1.z, num[6]);
        num[7] = fmaf(w, um * p1.w + u * q1.w, num[7]);
        den += w;
    }
#pragma unroll
    for (int off = 1; off < 16; off <<= 1) {
#pragma unroll
        for (int j = 0; j < 8; ++j) num[j] += __shfl_xor(num[j], off);
        den += __shfl_xor(den, off);
    }
    if (lane != 0) return;

    float inv = 1.f / (den + 1e-16f);
    float hp[8];
#pragma unroll
    for (int j = 0; j < 8; ++j) {
        float o = num[j] * inv + H1[(size_t)n * 8 + j] + bias1[j];
        hp[j] = (o > 0.f) ? o : expm1f(o);
    }
    float a[7], b[7], h[7];
#pragma unroll
    for (int j2 = 0; j2 < 7; ++j2) { a[j2] = 0.f; b[j2] = 0.f; h[j2] = 0.f; }
#pragma unroll
    for (int j = 0; j < 8; ++j) {
#pragma unroll
        for (int j2 = 0; j2 < 7; ++j2) {
            a[j2] = fmaf(hp[j], w2[j * 7 + j2], a[j2]);
            b[j2] = fmaf(hp[j], w2[56 + j * 7 + j2], b[j2]);
            h[j2] = fmaf(hp[j], root2[j * 7 + j2], h[j2]);
        }
    }
    float s0 = 0.f, s1 = 0.f, hA = 0.f;
#pragma unroll
    for (int j2 = 0; j2 < 7; ++j2) {
        s0 += a[j2] * att2[j2];
        s1 += b[j2] * att2[j2];
        hA += h[j2] * att2[7 + j2];
    }
    float4* xwout = reinterpret_cast<float4*>(XW2 + (size_t)n * 16);
    xwout[0] = make_float4(a[0], a[1], a[2], a[3]);
    xwout[1] = make_float4(a[4], a[5], a[6], 0.f);
    xwout[2] = make_float4(b[0], b[1], b[2], b[3]);
    xwout[3] = make_float4(b[4], b[5], b[6], 0.f);
    float4* hout = reinterpret_cast<float4*>(H2 + (size_t)n * 8);
    hout[0] = make_float4(h[0], h[1], h[2], h[3]);
    hout[1] = make_float4(h[4], h[5], h[6], 0.f);
    SC2[n] = make_float2(s0, s1);
    HA2[n] = hA;
}

// ---------------- Gather layer-2 (16 lanes per node) + fused log_softmax
__global__ __launch_bounds__(256) void gather2_kernel(
    const int* __restrict__ rowptr, const int2* __restrict__ recs,
    const float4* __restrict__ XW2v,
    const float2* __restrict__ SC2, const float* __restrict__ HA2,
    const float* __restrict__ H2, const float* __restrict__ bias2,
    float* __restrict__ out, int N)
{
    int tid = blockIdx.x * TPB + threadIdx.x;
    int n = tid >> 4;
    int lane = tid & 15;
    if (n >= N) return;
    int start = rowptr[n], end = rowptr[n + 1];
    float ha = HA2[n];
    float den = 0.f;
    float num[7];
#pragma unroll
    for (int j = 0; j < 7; ++j) num[j] = 0.f;

    for (int i = start + lane; i < end; i += 16) {
        int2 r = recs[i];
        int s = r.x;
        float u = __int_as_float(r.y);
        float um = 1.f - u;
        float2 sc = SC2[s];
        float raw = um * sc.x + u * sc.y + ha;
        float score = (raw > 0.f) ? raw : 0.2f * raw;
        float w = expf(score);
        const float4* xw = XW2v + (size_t)s * 4;
        float4 p0 = xw[0], p1 = xw[1], q0 = xw[2], q1 = xw[3];
        num[0] = fmaf(w, um * p0.x + u * q0.x, num[0]);
        num[1] = fmaf(w, um * p0.y + u * q0.y, num[1]);
        num[2] = fmaf(w, um * p0.z + u * q0.z, num[2]);
        num[3] = fmaf(w, um * p0.w + u * q0.w, num[3]);
        num[4] = fmaf(w, um * p1.x + u * q1.x, num[4]);
        num[5] = fmaf(w, um * p1.y + u * q1.y, num[5]);
        num[6] = fmaf(w, um * p1.z + u * q1.z, num[6]);
        den += w;
    }
#pragma unroll
    for (int off = 1; off < 16; off <<= 1) {
#pragma unroll
        for (int j = 0; j < 7; ++j) num[j] += __shfl_xor(num[j], off);
        den += __shfl_xor(den, off);
    }
    if (lane != 0) return;

    float inv = 1.f / (den + 1e-16f);
    float o[7];
    float mx = -1e30f;
#pragma unroll
    for (int j = 0; j < 7; ++j) {
        o[j] = fmaf(num[j], inv, H2[(size_t)n * 8 + j] + bias2[j]);
        mx = fmaxf(mx, o[j]);
    }
    float sum = 0.f;
#pragma unroll
    for (int j = 0; j < 7; ++j) sum += expf(o[j] - mx);
    float lse = mx + logf(sum);
#pragma unroll
    for (int j = 0; j < 7; ++j) out[(size_t)n * 7 + j] = o[j] - lse;
}

extern "C" void kernel_launch(void* const* d_in, const int* in_sizes, int n_in,
                              void* d_out, int out_size, void* d_ws, size_t ws_size,
                              hipStream_t stream) {
    const float* x      = (const float*)d_in[0];
    const int*   ei     = (const int*)d_in[1];
    const float* pseudo = (const float*)d_in[2];
    const float* w1     = (const float*)d_in[3];
    const float* root1  = (const float*)d_in[4];
    const float* att1   = (const float*)d_in[5];
    const float* bias1  = (const float*)d_in[6];
    const float* w2     = (const float*)d_in[7];
    const float* root2  = (const float*)d_in[8];
    const float* att2   = (const float*)d_in[9];
    const float* bias2  = (const float*)d_in[10];

    const int N = in_sizes[0] / F_IN;
    const int E = in_sizes[2];
    const size_t Ns = (size_t)N;

    float* ws   = (float*)d_ws;
    float* XW1  = ws;                       // 16N
    float* H1   = XW1 + 16 * Ns;            // 8N
    float2* SC1 = (float2*)(H1 + 8 * Ns);   // 2N floats
    float* HA1  = (float*)SC1 + 2 * Ns;     // N
    float* XW2  = HA1 + Ns;                 // 16N
    float* H2   = XW2 + 16 * Ns;            // 8N
    float2* SC2 = (float2*)(H2 + 8 * Ns);   // 2N
    float* HA2  = (float*)SC2 + 2 * Ns;     // N
    int*   cnt    = (int*)(HA2 + Ns);       // N
    int*   rowptr = cnt + Ns;               // N+1
    int*   bsums  = rowptr + Ns + 1;        // 128
    size_t off = (size_t)(bsums + 128) - (size_t)d_ws;
    off = (off + 7) & ~(size_t)7;
    int2*  recs = (int2*)((char*)d_ws + off);  // E records
    size_t woff = off + (size_t)E * sizeof(int2);
    woff = (woff + 15) & ~(size_t)15;
    short* WT = (short*)((char*)d_ws + woff);  // 32*KPAD bf16 (92 KB)

    int nblk  = (N + TPB - 1) / TPB;
    int eblk  = (E + TPB - 1) / TPB;
    int sblkA = (N + 1023) / 1024;
    int nb1   = (N + ROWS - 1) / ROWS;
    int gblk  = ((N * 16) + TPB - 1) / TPB;
    int prepn = (32 * KPAD > N) ? 32 * KPAD : N;
    int pblk  = (prepn + TPB - 1) / TPB;

    prep_kernel<<<pblk, TPB, 0, stream>>>(w1, root1, WT, cnt, N);
    node1_hist_kernel<<<nb1 + eblk, TPB, 0, stream>>>(
        x, WT, att1, XW1, H1, SC1, HA1, ei, cnt, N, E, nb1);
    scanA_kernel<<<sblkA, TPB, 0, stream>>>(cnt, rowptr, bsums, N);
    scanB_kernel<<<1, 128, 0, stream>>>(bsums, sblkA);
    scanC_kernel<<<nblk, TPB, 0, stream>>>(rowptr, cnt, bsums, N, E);
    scatter_kernel<<<eblk, TPB, 0, stream>>>(ei, pseudo, cnt, recs, E);
    gather1_kernel<<<gblk, TPB, 0, stream>>>(rowptr, recs, (const float4*)XW1, SC1, HA1,
                                             H1, bias1, w2, root2, att2,
                                             XW2, H2, SC2, HA2, N);
    gather2_kernel<<<gblk, TPB, 0, stream>>>(rowptr, recs, (const float4*)XW2, SC2, HA2,
                                             H2, bias2, (float*)d_out, N);
}